// Round 1
// baseline (586.932 us; speedup 1.0000x reference)
//
#include <hip/hip_runtime.h>

#define LDST 33  // 32 channels + 1 pad -> conflict-free column access

__device__ __forceinline__ float frcp_(float x){ return __builtin_amdgcn_rcpf(x); }
__device__ __forceinline__ float silu_(float x){ return x * frcp_(1.0f + __expf(-x)); }

// RBF basis: bas[g] = exp(-(( lnv - (-2 + g*4/7) ) / (4/7))^2) = exp(-(u-g)^2), u=(lnv+2)*1.75
// recurrence: b_{g+1} = b_g * e^{2u} * e^{-(2g+1)}  (2 transcendentals instead of 8)
__device__ __forceinline__ void basis8_(float lnv, float* bas){
  float u = (lnv + 2.0f) * 1.75f;
  float b = __expf(-u*u);
  float A = __expf(2.0f*u);
  bas[0]=b;
  b *= A * 0.36787944117144233f;   bas[1]=b;   // e^-1
  b *= A * 0.049787068367863944f;  bas[2]=b;   // e^-3
  b *= A * 0.006737946999085467f;  bas[3]=b;   // e^-5
  b *= A * 0.0009118819655545162f; bas[4]=b;   // e^-7
  b *= A * 1.2340980408667956e-4f; bas[5]=b;   // e^-9
  b *= A * 1.670170079024566e-5f;  bas[6]=b;   // e^-11
  b *= A * 2.2603294069810542e-6f; bas[7]=b;   // e^-13
}

// Force a pointer into SGPRs so that weight loads with loop-counter indices
// become s_load (scalar) instead of per-lane vector loads.
__device__ __forceinline__ const float* uptr_(const float* p){
  uint64_t v = (uint64_t)p;
  uint32_t lo = __builtin_amdgcn_readfirstlane((uint32_t)(v & 0xffffffffull));
  uint32_t hi = __builtin_amdgcn_readfirstlane((uint32_t)(v >> 32));
  return (const float*)(((uint64_t)hi << 32) | (uint64_t)lo);
}

// 32-dim FastKAN row: LN -> RBF(8) -> spline GEMM (8 outputs, o = osu*8+oo) + SiLU base path
__device__ __forceinline__ void kan32_(const float* vin, int osu,
                                       const float* __restrict__ lng, const float* __restrict__ lnb,
                                       const float* __restrict__ wsp, const float* __restrict__ wbp,
                                       const float* __restrict__ bbp, float* acc)
{
  float s1=0.f, s2=0.f;
  #pragma unroll
  for (int i=0;i<32;i++){ s1+=vin[i]; s2+=vin[i]*vin[i]; }
  float mu  = s1*(1.0f/32.0f);
  float var = s2*(1.0f/32.0f) - mu*mu;
  float rs  = rsqrtf(var + 1e-5f);
  #pragma unroll
  for (int oo=0;oo<8;oo++) acc[oo] = bbp[osu*8+oo];
  #pragma unroll 4
  for (int i=0;i<32;i++){
    float lnv = (vin[i]-mu)*rs*lng[i] + lnb[i];
    float bas[8]; basis8_(lnv, bas);
    #pragma unroll
    for (int oo=0;oo<8;oo++){
      const float* wr = wsp + (osu*8+oo)*256 + i*8;
      float a = bas[0]*wr[0]+bas[1]*wr[1]+bas[2]*wr[2]+bas[3]*wr[3]
              + bas[4]*wr[4]+bas[5]*wr[5]+bas[6]*wr[6]+bas[7]*wr[7];
      acc[oo] += a;
    }
    float sl = silu_(vin[i]);
    #pragma unroll
    for (int oo=0;oo<8;oo++) acc[oo] += sl * wbp[(osu*8+oo)*32 + i];
  }
}

__global__ __launch_bounds__(256)
void swin_kan_kernel(const float* __restrict__ x,
                     const float* __restrict__ pn_g, const float* __restrict__ pn_b,
                     const float* __restrict__ k1_ln_g, const float* __restrict__ k1_ln_b,
                     const float* __restrict__ k1_ws, const float* __restrict__ k1_wb, const float* __restrict__ k1_bb,
                     const float* __restrict__ k2_ln_g, const float* __restrict__ k2_ln_b,
                     const float* __restrict__ k2_ws, const float* __restrict__ k2_wb, const float* __restrict__ k2_bb,
                     const float* __restrict__ k3_ln_g, const float* __restrict__ k3_ln_b,
                     const float* __restrict__ k3_ws, const float* __restrict__ k3_wb, const float* __restrict__ k3_bb,
                     const float* __restrict__ k4_ln_g, const float* __restrict__ k4_ln_b,
                     const float* __restrict__ k4_ws, const float* __restrict__ k4_wb, const float* __restrict__ k4_bb,
                     float* __restrict__ out)
{
  __shared__ float xw[64][LDST];  // raw window  [pos=h*8+w][ch]
  __shared__ float yw[64][LDST];  // pre-LN'd
  __shared__ float zA[64][LDST];  // branch1 out, later z-sum
  __shared__ float zB[64][LDST];  // branch2 out

  const int t   = threadIdx.x;
  const int wid = blockIdx.x;
  const int b   = wid >> 10;
  const int hw  = (wid >> 5) & 31;
  const int ww  = wid & 31;
  const int h0  = hw*8, w0 = ww*8;

  // ---- phase 1: load window (each thread: one (ch,h) row of 8 w) ----
  {
    int ch = t & 31;
    int h  = t >> 5;
    const float* src = x + (((size_t)(b*32 + ch)*256 + (h0+h))*256 + w0);
    float4 v0 = *(const float4*)(src);
    float4 v1 = *(const float4*)(src + 4);
    int p = h*8;
    xw[p+0][ch]=v0.x; xw[p+1][ch]=v0.y; xw[p+2][ch]=v0.z; xw[p+3][ch]=v0.w;
    xw[p+4][ch]=v1.x; xw[p+5][ch]=v1.y; xw[p+6][ch]=v1.z; xw[p+7][ch]=v1.w;
  }
  __syncthreads();

  // ---- phase 2: pre-LN over 32 channels (4 lanes per position) ----
  {
    int pos  = t >> 2;
    int part = t & 3;
    float v[8]; float s1=0.f, s2=0.f;
    #pragma unroll
    for (int j=0;j<8;j++){ v[j]=xw[pos][part*8+j]; s1+=v[j]; s2+=v[j]*v[j]; }
    s1 += __shfl_xor(s1,1); s2 += __shfl_xor(s2,1);
    s1 += __shfl_xor(s1,2); s2 += __shfl_xor(s2,2);
    float mu  = s1*(1.0f/32.0f);
    float var = s2*(1.0f/32.0f) - mu*mu;
    float rs  = rsqrtf(var + 1e-5f);
    #pragma unroll
    for (int j=0;j<8;j++){
      int c = part*8+j;
      yw[pos][c] = (v[j]-mu)*rs*pn_g[c] + pn_b[c];
    }
  }
  __syncthreads();

  // ---- phase 3: branch1 (waves 0-1) + branch2 (waves 2-3), 16-dim FastKAN ----
  {
    const bool br2 = (t >= 128);
    const int r  = t & 127;
    const int rw = r >> 4;   // w (b1) or h (b2)
    const int cc = r & 15;
    const float* lng = uptr_(br2 ? k2_ln_g : k1_ln_g);
    const float* lnb = uptr_(br2 ? k2_ln_b : k1_ln_b);
    const float* wsp = uptr_(br2 ? k2_ws  : k1_ws);
    const float* wbp = uptr_(br2 ? k2_wb  : k1_wb);
    const float* bbp = uptr_(br2 ? k2_bb  : k1_bb);

    float v[16];
    if (!br2) {
      #pragma unroll
      for (int h=0;h<8;h++){ v[h*2+0]=yw[h*8+rw][cc*2+0]; v[h*2+1]=yw[h*8+rw][cc*2+1]; }
    } else {
      #pragma unroll
      for (int w=0;w<8;w++){ v[w*2+0]=yw[rw*8+w][cc*2+0]; v[w*2+1]=yw[rw*8+w][cc*2+1]; }
    }
    float s1=0.f,s2=0.f;
    #pragma unroll
    for (int j=0;j<16;j++){ s1+=v[j]; s2+=v[j]*v[j]; }
    float mu  = s1*(1.0f/16.0f);
    float var = s2*(1.0f/16.0f)-mu*mu;
    float rs  = rsqrtf(var+1e-5f);
    float acc[16];
    #pragma unroll
    for (int o=0;o<16;o++) acc[o]=bbp[o];
    #pragma unroll 4
    for (int i=0;i<16;i++){
      float lnv = (v[i]-mu)*rs*lng[i] + lnb[i];
      float bas[8]; basis8_(lnv, bas);
      #pragma unroll
      for (int o=0;o<16;o++){
        const float* wr = wsp + o*128 + i*8;
        float a = bas[0]*wr[0]+bas[1]*wr[1]+bas[2]*wr[2]+bas[3]*wr[3]
                + bas[4]*wr[4]+bas[5]*wr[5]+bas[6]*wr[6]+bas[7]*wr[7];
        acc[o] += a;
      }
      float sl = silu_(v[i]);
      #pragma unroll
      for (int o=0;o<16;o++) acc[o] += sl * wbp[o*16 + i];
    }
    if (!br2) {
      #pragma unroll
      for (int h=0;h<8;h++){ zA[h*8+rw][cc*2+0]=acc[h*2+0]; zA[h*8+rw][cc*2+1]=acc[h*2+1]; }
    } else {
      #pragma unroll
      for (int w=0;w<8;w++){ zB[rw*8+w][cc*2+0]=acc[w*2+0]; zB[rw*8+w][cc*2+1]=acc[w*2+1]; }
    }
  }
  __syncthreads();

  // ---- phase 4: branch3 (32-dim FastKAN on yw) + z = a + d + e (in-place into zA) ----
  {
    const int pos = t & 63;
    const int osu = __builtin_amdgcn_readfirstlane(t >> 6); // wave-uniform output slice
    float v[32];
    #pragma unroll
    for (int c=0;c<32;c++) v[c]=yw[pos][c];
    float acc[8];
    kan32_(v, osu, k3_ln_g, k3_ln_b, k3_ws, k3_wb, k3_bb, acc);
    #pragma unroll
    for (int oo=0;oo<8;oo++){
      int c = osu*8+oo;
      zA[pos][c] = zA[pos][c] + zB[pos][c] + acc[oo];
    }
  }
  __syncthreads();

  // ---- phase 5: output KAN (k4) + residual + store ----
  {
    const int pos = t & 63;
    const int osu = __builtin_amdgcn_readfirstlane(t >> 6);
    float v[32];
    #pragma unroll
    for (int c=0;c<32;c++) v[c]=zA[pos][c];
    float acc[8];
    kan32_(v, osu, k4_ln_g, k4_ln_b, k4_ws, k4_wb, k4_bb, acc);
    const int h = pos >> 3, w = pos & 7;
    #pragma unroll
    for (int oo=0;oo<8;oo++){
      int c = osu*8+oo;
      float r = acc[oo] + xw[pos][c];
      out[(((size_t)(b*32 + c))*256 + (h0+h))*256 + (w0 + w)] = r;
    }
  }
}

extern "C" void kernel_launch(void* const* d_in, const int* in_sizes, int n_in,
                              void* d_out, int out_size, void* d_ws, size_t ws_size,
                              hipStream_t stream) {
  const float* x      = (const float*)d_in[0];
  const float* pn_g   = (const float*)d_in[1];
  const float* pn_b   = (const float*)d_in[2];
  const float* k1_ln_g= (const float*)d_in[3];
  const float* k1_ln_b= (const float*)d_in[4];
  const float* k1_ws  = (const float*)d_in[5];
  const float* k1_wb  = (const float*)d_in[6];
  const float* k1_bb  = (const float*)d_in[7];
  const float* k2_ln_g= (const float*)d_in[8];
  const float* k2_ln_b= (const float*)d_in[9];
  const float* k2_ws  = (const float*)d_in[10];
  const float* k2_wb  = (const float*)d_in[11];
  const float* k2_bb  = (const float*)d_in[12];
  const float* k3_ln_g= (const float*)d_in[13];
  const float* k3_ln_b= (const float*)d_in[14];
  const float* k3_ws  = (const float*)d_in[15];
  const float* k3_wb  = (const float*)d_in[16];
  const float* k3_bb  = (const float*)d_in[17];
  const float* k4_ln_g= (const float*)d_in[18];
  const float* k4_ln_b= (const float*)d_in[19];
  const float* k4_ws  = (const float*)d_in[20];
  const float* k4_wb  = (const float*)d_in[21];
  const float* k4_bb  = (const float*)d_in[22];
  float* out = (float*)d_out;

  dim3 grid(4096), block(256);
  hipLaunchKernelGGL(swin_kan_kernel, grid, block, 0, stream,
                     x, pn_g, pn_b,
                     k1_ln_g, k1_ln_b, k1_ws, k1_wb, k1_bb,
                     k2_ln_g, k2_ln_b, k2_ws, k2_wb, k2_bb,
                     k3_ln_g, k3_ln_b, k3_ws, k3_wb, k3_bb,
                     k4_ln_g, k4_ln_b, k4_ws, k4_wb, k4_bb,
                     out);
}

// Round 2
// 110.083 us; speedup vs baseline: 5.3317x; 5.3317x over previous
//
#include <hip/hip_runtime.h>

typedef __attribute__((ext_vector_type(8))) short  s8v;
typedef __attribute__((ext_vector_type(8))) __bf16 b8v;
typedef __attribute__((ext_vector_type(4))) float  f4v;

#define LDST 33
#define KP1  168   // padded K stride (elems) for k1/k2 basis rows (logical 160)
#define KP3  296   // padded K stride for k3/k4 basis rows (logical 288)

// Wbf (bf16) layout in d_ws:
//  W1 [16][160] @ 0      (cols 0..127 = k1_ws, 128..143 = k1_wb, 144..159 = 0)
//  W2 [16][160] @ 2560
//  W3 [32][288] @ 5120   (cols 0..255 = k3_ws, 256..287 = k3_wb)
//  W4 [32][288] @ 14336  ; total 23552 elems
#define W2_OFF 2560
#define W3_OFF 5120
#define W4_OFF 14336
#define W_TOTAL 23552

__device__ __forceinline__ float frcp_(float x){ return __builtin_amdgcn_rcpf(x); }
__device__ __forceinline__ float silu_(float x){ return x * frcp_(1.0f + __expf(-x)); }

// bas[g] = exp(-(u-g)^2), u=(lnv+2)*1.75 ; recurrence: b_{g+1}=b_g * e^{2u} * e^{-(2g+1)}
__device__ __forceinline__ b8v basis8bf_(float lnv){
  float u = (lnv + 2.0f) * 1.75f;
  float b = __expf(-u*u);
  float A = __expf(2.0f*u);
  b8v r;
  r[0] = (__bf16)b;
  b *= A * 0.36787944117144233f;   r[1] = (__bf16)b;
  b *= A * 0.049787068367863944f;  r[2] = (__bf16)b;
  b *= A * 0.006737946999085467f;  r[3] = (__bf16)b;
  b *= A * 0.0009118819655545162f; r[4] = (__bf16)b;
  b *= A * 1.2340980408667956e-4f; r[5] = (__bf16)b;
  b *= A * 1.670170079024566e-5f;  r[6] = (__bf16)b;
  b *= A * 2.2603294069810542e-6f; r[7] = (__bf16)b;
  return r;
}

// ---- prep kernel: pack all KAN weights into bf16 concat layout in d_ws ----
__global__ void prep_w(const float* __restrict__ ws1, const float* __restrict__ wb1,
                       const float* __restrict__ ws2, const float* __restrict__ wb2,
                       const float* __restrict__ ws3, const float* __restrict__ wb3,
                       const float* __restrict__ ws4, const float* __restrict__ wb4,
                       __bf16* __restrict__ W){
  int idx = blockIdx.x*256 + threadIdx.x;
  if (idx >= W_TOTAL) return;
  float v;
  if (idx < W3_OFF){
    int base = (idx >= W2_OFF) ? W2_OFF : 0;
    const float* ws = base ? ws2 : ws1;
    const float* wb = base ? wb2 : wb1;
    int r = idx - base; int o = r/160, k = r%160;
    v = (k < 128) ? ws[o*128 + k] : ((k < 144) ? wb[o*16 + (k-128)] : 0.0f);
  } else {
    int base = (idx >= W4_OFF) ? W4_OFF : W3_OFF;
    const float* ws = (base == W4_OFF) ? ws4 : ws3;
    const float* wb = (base == W4_OFF) ? wb4 : wb3;
    int r = idx - base; int o = r/288, k = r%288;
    v = (k < 256) ? ws[o*256 + k] : wb[o*32 + (k-256)];
  }
  W[idx] = (__bf16)v;
}

// ---- 16-dim basis phase (k1: second=false, k2: second=true) ----
__device__ __forceinline__ void basis16_phase(int t, bool second,
    const float (*yw)[LDST], __bf16* Abuf,
    const float* __restrict__ lng, const float* __restrict__ lnb)
{
  const int r = t >> 1, half = t & 1;
  const int a0 = r >> 4, c = r & 15;   // a0 = w (k1) or h (k2)
  float v[8];
  #pragma unroll
  for (int j=0;j<8;j++){
    int i = half*8 + j; int p = i >> 1; int s = i & 1;
    int pos = second ? (a0*8 + p) : (p*8 + a0);
    v[j] = yw[pos][2*c + s];
  }
  float s1=0.f, s2=0.f;
  #pragma unroll
  for (int j=0;j<8;j++){ s1 += v[j]; s2 += v[j]*v[j]; }
  s1 += __shfl_xor(s1,1); s2 += __shfl_xor(s2,1);
  float mu  = s1*(1.0f/16.0f);
  float var = s2*(1.0f/16.0f) - mu*mu;
  float rs  = rsqrtf(var + 1e-5f);
  b8v slv;
  #pragma unroll
  for (int j=0;j<8;j++){
    int i = half*8 + j;
    float lnv = (v[j]-mu)*rs*lng[i] + lnb[i];
    *(b8v*)&Abuf[r*KP1 + i*8] = basis8bf_(lnv);
    slv[j] = (__bf16)silu_(v[j]);
  }
  *(b8v*)&Abuf[r*KP1 + 128 + half*8] = slv;
  s8v zz = 0;
  *(s8v*)&Abuf[r*KP1 + 144 + half*8] = zz;
}

// ---- 32-dim basis phase (k3 from yw, k4 from zacc) ----
__device__ __forceinline__ void basis32_phase(int t,
    const float (*src)[LDST], __bf16* Abuf,
    const float* __restrict__ lng, const float* __restrict__ lnb)
{
  const int r = t >> 2, part = t & 3;
  float v[8];
  #pragma unroll
  for (int j=0;j<8;j++) v[j] = src[r][part*8 + j];
  float s1=0.f, s2=0.f;
  #pragma unroll
  for (int j=0;j<8;j++){ s1 += v[j]; s2 += v[j]*v[j]; }
  s1 += __shfl_xor(s1,1); s2 += __shfl_xor(s2,1);
  s1 += __shfl_xor(s1,2); s2 += __shfl_xor(s2,2);
  float mu  = s1*(1.0f/32.0f);
  float var = s2*(1.0f/32.0f) - mu*mu;
  float rs  = rsqrtf(var + 1e-5f);
  b8v slv;
  #pragma unroll
  for (int j=0;j<8;j++){
    int i = part*8 + j;
    float lnv = (v[j]-mu)*rs*lng[i] + lnb[i];
    *(b8v*)&Abuf[r*KP3 + i*8] = basis8bf_(lnv);
    slv[j] = (__bf16)silu_(v[j]);
  }
  *(b8v*)&Abuf[r*KP3 + 256 + part*8] = slv;
}

__global__ __launch_bounds__(256,2)
void swin_kan_mfma(const float* __restrict__ x,
                   const float* __restrict__ pn_g, const float* __restrict__ pn_b,
                   const float* __restrict__ k1_ln_g, const float* __restrict__ k1_ln_b, const float* __restrict__ k1_bb,
                   const float* __restrict__ k2_ln_g, const float* __restrict__ k2_ln_b, const float* __restrict__ k2_bb,
                   const float* __restrict__ k3_ln_g, const float* __restrict__ k3_ln_b, const float* __restrict__ k3_bb,
                   const float* __restrict__ k4_ln_g, const float* __restrict__ k4_ln_b, const float* __restrict__ k4_bb,
                   const __bf16* __restrict__ Wbf,
                   float* __restrict__ out)
{
  __shared__ __attribute__((aligned(16))) float xw[64][LDST];
  __shared__ __attribute__((aligned(16))) float yw[64][LDST];
  __shared__ __attribute__((aligned(16))) float zacc[64][LDST];
  __shared__ __attribute__((aligned(16))) __bf16 Abuf[128*KP1];  // 43008 B, also holds [64][KP3]

  const int t   = threadIdx.x;
  const int wid = blockIdx.x;
  const int b   = wid >> 10;
  const int h0  = ((wid >> 5) & 31) * 8;
  const int w0  = (wid & 31) * 8;
  const int wave = t >> 6, lane = t & 63;
  const int fn = lane & 15, kg = lane >> 4;   // fragment indices

  // phase 1: load window
  {
    int ch = t & 31, h = t >> 5;
    const float* src = x + (((size_t)(b*32 + ch)*256 + (h0+h))*256 + w0);
    float4 v0 = *(const float4*)(src);
    float4 v1 = *(const float4*)(src + 4);
    int p = h*8;
    xw[p+0][ch]=v0.x; xw[p+1][ch]=v0.y; xw[p+2][ch]=v0.z; xw[p+3][ch]=v0.w;
    xw[p+4][ch]=v1.x; xw[p+5][ch]=v1.y; xw[p+6][ch]=v1.z; xw[p+7][ch]=v1.w;
  }
  __syncthreads();

  // phase 2: pre-LN
  {
    int pos = t >> 2, part = t & 3;
    float v[8]; float s1=0.f, s2=0.f;
    #pragma unroll
    for (int j=0;j<8;j++){ v[j]=xw[pos][part*8+j]; s1+=v[j]; s2+=v[j]*v[j]; }
    s1 += __shfl_xor(s1,1); s2 += __shfl_xor(s2,1);
    s1 += __shfl_xor(s1,2); s2 += __shfl_xor(s2,2);
    float mu  = s1*(1.0f/32.0f);
    float var = s2*(1.0f/32.0f) - mu*mu;
    float rs  = rsqrtf(var + 1e-5f);
    #pragma unroll
    for (int j=0;j<8;j++){
      int c = part*8+j;
      yw[pos][c] = (v[j]-mu)*rs*pn_g[c] + pn_b[c];
    }
  }
  __syncthreads();

  // phase 3: basis k1
  basis16_phase(t, false, yw, Abuf, k1_ln_g, k1_ln_b);
  __syncthreads();

  // phase 4: GEMM1 (M=128,N=16,K=160) -> zacc =
  {
    const __bf16* Wp = Wbf;
    s8v bfr[5];
    #pragma unroll
    for (int ks=0;ks<5;ks++) bfr[ks] = *(const s8v*)&Wp[fn*160 + ks*32 + kg*8];
    float bias = k1_bb[fn];
    #pragma unroll
    for (int mi=0;mi<2;mi++){
      int mt = wave*2 + mi;
      f4v acc = {bias,bias,bias,bias};
      #pragma unroll
      for (int ks=0;ks<5;ks++){
        s8v a = *(const s8v*)&Abuf[(mt*16 + fn)*KP1 + ks*32 + kg*8];
        acc = __builtin_amdgcn_mfma_f32_16x16x32_bf16(a, bfr[ks], acc, 0,0,0);
      }
      #pragma unroll
      for (int rg=0;rg<4;rg++){
        int m = mt*16 + kg*4 + rg;
        zacc[(fn>>1)*8 + (m>>4)][2*(m&15) + (fn&1)] = acc[rg];
      }
    }
  }
  __syncthreads();

  // phase 5: basis k2
  basis16_phase(t, true, yw, Abuf, k2_ln_g, k2_ln_b);
  __syncthreads();

  // phase 6: GEMM2 -> zacc +=
  {
    const __bf16* Wp = Wbf + W2_OFF;
    s8v bfr[5];
    #pragma unroll
    for (int ks=0;ks<5;ks++) bfr[ks] = *(const s8v*)&Wp[fn*160 + ks*32 + kg*8];
    float bias = k2_bb[fn];
    #pragma unroll
    for (int mi=0;mi<2;mi++){
      int mt = wave*2 + mi;
      f4v acc = {bias,bias,bias,bias};
      #pragma unroll
      for (int ks=0;ks<5;ks++){
        s8v a = *(const s8v*)&Abuf[(mt*16 + fn)*KP1 + ks*32 + kg*8];
        acc = __builtin_amdgcn_mfma_f32_16x16x32_bf16(a, bfr[ks], acc, 0,0,0);
      }
      #pragma unroll
      for (int rg=0;rg<4;rg++){
        int m = mt*16 + kg*4 + rg;
        zacc[(m>>4)*8 + (fn>>1)][2*(m&15) + (fn&1)] += acc[rg];
      }
    }
  }
  __syncthreads();

  // phase 7: basis k3 (from yw)
  basis32_phase(t, yw, Abuf, k3_ln_g, k3_ln_b);
  __syncthreads();

  // phase 8: GEMM3 (M=64,N=32,K=288) -> zacc +=
  {
    const __bf16* Wp = Wbf + W3_OFF;
    const int arow = (wave*16 + fn)*KP3;
    for (int nt=0; nt<2; nt++){
      int n = nt*16 + fn;
      float bias = k3_bb[n];
      f4v acc = {bias,bias,bias,bias};
      #pragma unroll
      for (int ks=0;ks<9;ks++){
        s8v a = *(const s8v*)&Abuf[arow + ks*32 + kg*8];
        s8v bf = *(const s8v*)&Wp[n*288 + ks*32 + kg*8];
        acc = __builtin_amdgcn_mfma_f32_16x16x32_bf16(a, bf, acc, 0,0,0);
      }
      #pragma unroll
      for (int rg=0;rg<4;rg++){
        int m = wave*16 + kg*4 + rg;
        zacc[m][n] += acc[rg];
      }
    }
  }
  __syncthreads();

  // phase 9: basis k4 (from zacc = z)
  basis32_phase(t, zacc, Abuf, k4_ln_g, k4_ln_b);
  __syncthreads();

  // phase 10: GEMM4 -> yw = result + residual(xw)
  {
    const __bf16* Wp = Wbf + W4_OFF;
    const int arow = (wave*16 + fn)*KP3;
    for (int nt=0; nt<2; nt++){
      int n = nt*16 + fn;
      float bias = k4_bb[n];
      f4v acc = {bias,bias,bias,bias};
      #pragma unroll
      for (int ks=0;ks<9;ks++){
        s8v a = *(const s8v*)&Abuf[arow + ks*32 + kg*8];
        s8v bf = *(const s8v*)&Wp[n*288 + ks*32 + kg*8];
        acc = __builtin_amdgcn_mfma_f32_16x16x32_bf16(a, bf, acc, 0,0,0);
      }
      #pragma unroll
      for (int rg=0;rg<4;rg++){
        int m = wave*16 + kg*4 + rg;
        yw[m][n] = acc[rg] + xw[m][n];
      }
    }
  }
  __syncthreads();

  // phase 11: coalesced store
  {
    int ch = t & 31, h = t >> 5;
    float* dst = out + (((size_t)(b*32 + ch)*256 + (h0+h))*256 + w0);
    int p = h*8;
    float4 v0 = { yw[p+0][ch], yw[p+1][ch], yw[p+2][ch], yw[p+3][ch] };
    float4 v1 = { yw[p+4][ch], yw[p+5][ch], yw[p+6][ch], yw[p+7][ch] };
    *(float4*)(dst)     = v0;
    *(float4*)(dst + 4) = v1;
  }
}

extern "C" void kernel_launch(void* const* d_in, const int* in_sizes, int n_in,
                              void* d_out, int out_size, void* d_ws, size_t ws_size,
                              hipStream_t stream) {
  const float* x      = (const float*)d_in[0];
  const float* pn_g   = (const float*)d_in[1];
  const float* pn_b   = (const float*)d_in[2];
  const float* k1_ln_g= (const float*)d_in[3];
  const float* k1_ln_b= (const float*)d_in[4];
  const float* k1_ws  = (const float*)d_in[5];
  const float* k1_wb  = (const float*)d_in[6];
  const float* k1_bb  = (const float*)d_in[7];
  const float* k2_ln_g= (const float*)d_in[8];
  const float* k2_ln_b= (const float*)d_in[9];
  const float* k2_ws  = (const float*)d_in[10];
  const float* k2_wb  = (const float*)d_in[11];
  const float* k2_bb  = (const float*)d_in[12];
  const float* k3_ln_g= (const float*)d_in[13];
  const float* k3_ln_b= (const float*)d_in[14];
  const float* k3_ws  = (const float*)d_in[15];
  const float* k3_wb  = (const float*)d_in[16];
  const float* k3_bb  = (const float*)d_in[17];
  const float* k4_ln_g= (const float*)d_in[18];
  const float* k4_ln_b= (const float*)d_in[19];
  const float* k4_ws  = (const float*)d_in[20];
  const float* k4_wb  = (const float*)d_in[21];
  const float* k4_bb  = (const float*)d_in[22];
  float* out = (float*)d_out;
  __bf16* Wbf = (__bf16*)d_ws;

  hipLaunchKernelGGL(prep_w, dim3((W_TOTAL+255)/256), dim3(256), 0, stream,
                     k1_ws, k1_wb, k2_ws, k2_wb, k3_ws, k3_wb, k4_ws, k4_wb, Wbf);

  hipLaunchKernelGGL(swin_kan_mfma, dim3(4096), dim3(256), 0, stream,
                     x, pn_g, pn_b,
                     k1_ln_g, k1_ln_b, k1_bb,
                     k2_ln_g, k2_ln_b, k2_bb,
                     k3_ln_g, k3_ln_b, k3_bb,
                     k4_ln_g, k4_ln_b, k4_bb,
                     Wbf, out);
}

// Round 3
// 78.006 us; speedup vs baseline: 7.5242x; 1.4112x over previous
//
#include <hip/hip_runtime.h>

typedef __attribute__((ext_vector_type(8))) short  s8v;
typedef __attribute__((ext_vector_type(8))) __bf16 b8v;
typedef __attribute__((ext_vector_type(4))) float  f4v;
typedef __attribute__((ext_vector_type(2))) float  f2v;

#define LDST 36   // 16B-aligned rows; bank math gives <=2-way on hot paths

// Wbf (bf16) layout in d_ws:
//  W1 [16][160] @ 0      (k<128: ws; k in [128,160): kg=(k-128)>>3, j=(k-128)&7 -> j<4 ? wb[o][j*4+kg] : 0)
//  W2 [16][160] @ 2560
//  W3 [32][288] @ 5120   (k<256: ws; k in [256,288): kg,j -> wb[o][j*4+kg])
//  W4 [32][288] @ 14336
#define W2_OFF 2560
#define W3_OFF 5120
#define W4_OFF 14336
#define W_TOTAL 23552

__device__ __forceinline__ float frcp_(float x){ return __builtin_amdgcn_rcpf(x); }
__device__ __forceinline__ float silu_(float x){ return x * frcp_(1.0f + __expf(-x)); }

__device__ __forceinline__ s8v b2s(b8v v){ union { b8v b; s8v s; } u; u.b = v; return u.s; }

// bas[g] = exp(-(u-g)^2), u=(lnv+2)*1.75 ; recurrence uses 2 transcendentals
__device__ __forceinline__ b8v basis8bf_(float lnv){
  float u = (lnv + 2.0f) * 1.75f;
  float b = __expf(-u*u);
  float A = __expf(2.0f*u);
  b8v r;
  r[0] = (__bf16)b;
  b *= A * 0.36787944117144233f;   r[1] = (__bf16)b;
  b *= A * 0.049787068367863944f;  r[2] = (__bf16)b;
  b *= A * 0.006737946999085467f;  r[3] = (__bf16)b;
  b *= A * 0.0009118819655545162f; r[4] = (__bf16)b;
  b *= A * 1.2340980408667956e-4f; r[5] = (__bf16)b;
  b *= A * 1.670170079024566e-5f;  r[6] = (__bf16)b;
  b *= A * 2.2603294069810542e-6f; r[7] = (__bf16)b;
  return r;
}

__global__ void prep_w(const float* __restrict__ ws1, const float* __restrict__ wb1,
                       const float* __restrict__ ws2, const float* __restrict__ wb2,
                       const float* __restrict__ ws3, const float* __restrict__ wb3,
                       const float* __restrict__ ws4, const float* __restrict__ wb4,
                       __bf16* __restrict__ W){
  int idx = blockIdx.x*256 + threadIdx.x;
  if (idx >= W_TOTAL) return;
  float v;
  if (idx < W3_OFF){
    int base = (idx >= W2_OFF) ? W2_OFF : 0;
    const float* ws = base ? ws2 : ws1;
    const float* wb = base ? wb2 : wb1;
    int r = idx - base; int o = r/160, k = r%160;
    if (k < 128) v = ws[o*128 + k];
    else { int kk = k-128; int kg = kk>>3, j = kk&7; v = (j<4) ? wb[o*16 + j*4 + kg] : 0.0f; }
  } else {
    int base = (idx >= W4_OFF) ? W4_OFF : W3_OFF;
    const float* ws = (base == W4_OFF) ? ws4 : ws3;
    const float* wb = (base == W4_OFF) ? wb4 : wb3;
    int r = idx - base; int o = r/288, k = r%288;
    if (k < 256) v = ws[o*256 + k];
    else { int kk = k-256; int kg = kk>>3, j = kk&7; v = wb[o*32 + j*4 + kg]; }
  }
  W[idx] = (__bf16)v;
}

__global__ __launch_bounds__(256,4)
void swin_kan_mfma(const float* __restrict__ x,
                   const float* __restrict__ pn_g, const float* __restrict__ pn_b,
                   const float* __restrict__ k1_ln_g, const float* __restrict__ k1_ln_b, const float* __restrict__ k1_bb,
                   const float* __restrict__ k2_ln_g, const float* __restrict__ k2_ln_b, const float* __restrict__ k2_bb,
                   const float* __restrict__ k3_ln_g, const float* __restrict__ k3_ln_b, const float* __restrict__ k3_bb,
                   const float* __restrict__ k4_ln_g, const float* __restrict__ k4_ln_b, const float* __restrict__ k4_bb,
                   const __bf16* __restrict__ Wbf,
                   float* __restrict__ out)
{
  __shared__ __attribute__((aligned(16))) float xw[64][LDST];
  __shared__ __attribute__((aligned(16))) float yw[64][LDST];
  __shared__ __attribute__((aligned(16))) float zA[64][LDST];
  __shared__ __attribute__((aligned(16))) float zB[64][LDST];

  const int t   = threadIdx.x;
  const int bid = blockIdx.x;
  const int wid = (bid & 7)*512 + (bid >> 3);   // XCD-chunked swizzle (4096 % 8 == 0)
  const int b   = wid >> 10;
  const int h0  = ((wid >> 5) & 31) * 8;
  const int w0  = (wid & 31) * 8;
  const int wave = t >> 6, lane = t & 63;
  const int fn = lane & 15, kg = lane >> 4;

  // ---- phase 1: load window ----
  {
    int ch = t & 31, h = t >> 5;
    const float* src = x + (((size_t)(b*32 + ch)*256 + (h0+h))*256 + w0);
    float4 v0 = *(const float4*)(src);
    float4 v1 = *(const float4*)(src + 4);
    int p = h*8;
    xw[p+0][ch]=v0.x; xw[p+1][ch]=v0.y; xw[p+2][ch]=v0.z; xw[p+3][ch]=v0.w;
    xw[p+4][ch]=v1.x; xw[p+5][ch]=v1.y; xw[p+6][ch]=v1.z; xw[p+7][ch]=v1.w;
  }
  __syncthreads();

  // ---- phase 2: pre-LN (vectorized LDS access, conflict-free-at-min b128) ----
  {
    int pos = t >> 2, part = t & 3;
    f4v a = *(const f4v*)&xw[pos][part*8];
    f4v c = *(const f4v*)&xw[pos][part*8+4];
    float s1 = a[0]+a[1]+a[2]+a[3]+c[0]+c[1]+c[2]+c[3];
    float s2 = a[0]*a[0]+a[1]*a[1]+a[2]*a[2]+a[3]*a[3]
             + c[0]*c[0]+c[1]*c[1]+c[2]*c[2]+c[3]*c[3];
    s1 += __shfl_xor(s1,1); s2 += __shfl_xor(s2,1);
    s1 += __shfl_xor(s1,2); s2 += __shfl_xor(s2,2);
    float mu  = s1*(1.0f/32.0f);
    float var = s2*(1.0f/32.0f) - mu*mu;
    float rs  = rsqrtf(var + 1e-5f);
    f4v g0 = *(const f4v*)&pn_g[part*8], g1 = *(const f4v*)&pn_g[part*8+4];
    f4v b0 = *(const f4v*)&pn_b[part*8], b1 = *(const f4v*)&pn_b[part*8+4];
    f4v o0, o1;
    #pragma unroll
    for (int j=0;j<4;j++){ o0[j] = (a[j]-mu)*rs*g0[j] + b0[j]; o1[j] = (c[j]-mu)*rs*g1[j] + b1[j]; }
    *(f4v*)&yw[pos][part*8]   = o0;
    *(f4v*)&yw[pos][part*8+4] = o1;
  }
  __syncthreads();

  // ---- phase 3: GEMM1 (waves 0,1 -> zA) & GEMM2 (waves 2,3 -> zB), basis in registers ----
  {
    const bool br2 = (wave >= 2);
    const __bf16* Wp  = Wbf + (br2 ? W2_OFF : 0);
    const float* lng = br2 ? k2_ln_g : k1_ln_g;
    const float* lnb = br2 ? k2_ln_b : k1_ln_b;
    const float* bbp = br2 ? k2_bb  : k1_bb;
    s8v wfr[5];
    #pragma unroll
    for (int ks=0;ks<5;ks++) wfr[ks] = *(const s8v*)&Wp[fn*160 + ks*32 + kg*8];
    f4v bias = *(const f4v*)&bbp[kg*4];
    float lg[4], lb[4];
    #pragma unroll
    for (int ks=0;ks<4;ks++){ int i = ks*4+kg; lg[ks]=lng[i]; lb[ks]=lnb[i]; }

    #pragma unroll
    for (int mi=0; mi<4; mi++){
      const int ck = (wave & 1)*4 + mi;  // row chunk: rows r = ck*16 + fn
      float v[4];
      #pragma unroll
      for (int ks=0;ks<4;ks++){
        int i = ks*4 + kg;
        v[ks] = br2 ? yw[ck*8 + (i>>1)][2*fn + (i&1)]
                    : yw[(i>>1)*8 + ck][2*fn + (i&1)];
      }
      float s1 = v[0]+v[1]+v[2]+v[3];
      float s2 = v[0]*v[0]+v[1]*v[1]+v[2]*v[2]+v[3]*v[3];
      s1 += __shfl_xor(s1,16); s2 += __shfl_xor(s2,16);
      s1 += __shfl_xor(s1,32); s2 += __shfl_xor(s2,32);
      float mu  = s1*(1.0f/16.0f);
      float var = s2*(1.0f/16.0f) - mu*mu;
      float rs  = rsqrtf(var + 1e-5f);

      f4v acc = bias;
      #pragma unroll
      for (int ks=0;ks<4;ks++){
        float lnv = (v[ks]-mu)*rs*lg[ks] + lb[ks];
        acc = __builtin_amdgcn_mfma_f32_16x16x32_bf16(wfr[ks], b2s(basis8bf_(lnv)), acc, 0,0,0);
      }
      b8v bb = {};
      #pragma unroll
      for (int j=0;j<4;j++) bb[j] = (__bf16)silu_(v[j]);
      acc = __builtin_amdgcn_mfma_f32_16x16x32_bf16(wfr[4], b2s(bb), acc, 0,0,0);

      // writeback: D[o=kg*4+rg][r=ck*16+fn]
      if (!br2){
        *(f2v*)&zA[(2*kg+0)*8 + ck][2*fn] = f2v{acc[0], acc[1]};
        *(f2v*)&zA[(2*kg+1)*8 + ck][2*fn] = f2v{acc[2], acc[3]};
      } else {
        *(f2v*)&zB[ck*8 + 2*kg+0][2*fn] = f2v{acc[0], acc[1]};
        *(f2v*)&zB[ck*8 + 2*kg+1][2*fn] = f2v{acc[2], acc[3]};
      }
    }
  }
  __syncthreads();

  // ---- phase 4: GEMM3 (k3 on yw) + z = a + d + e -> zA ----
  {
    const int r = wave*16 + fn;   // spatial pos 0..63
    float v[8];
    #pragma unroll
    for (int ks=0;ks<8;ks++) v[ks] = yw[r][ks*4 + kg];
    float s1=0.f, s2=0.f;
    #pragma unroll
    for (int ks=0;ks<8;ks++){ s1 += v[ks]; s2 += v[ks]*v[ks]; }
    s1 += __shfl_xor(s1,16); s2 += __shfl_xor(s2,16);
    s1 += __shfl_xor(s1,32); s2 += __shfl_xor(s2,32);
    float mu  = s1*(1.0f/32.0f);
    float var = s2*(1.0f/32.0f) - mu*mu;
    float rs  = rsqrtf(var + 1e-5f);

    f4v acc0 = *(const f4v*)&k3_bb[kg*4];
    f4v acc1 = *(const f4v*)&k3_bb[16 + kg*4];
    #pragma unroll
    for (int ks=0;ks<8;ks++){
      float lnv = (v[ks]-mu)*rs*k3_ln_g[ks*4+kg] + k3_ln_b[ks*4+kg];
      s8v bf = b2s(basis8bf_(lnv));
      s8v wa = *(const s8v*)&Wbf[W3_OFF + fn*288      + ks*32 + kg*8];
      s8v wb = *(const s8v*)&Wbf[W3_OFF + (16+fn)*288 + ks*32 + kg*8];
      acc0 = __builtin_amdgcn_mfma_f32_16x16x32_bf16(wa, bf, acc0, 0,0,0);
      acc1 = __builtin_amdgcn_mfma_f32_16x16x32_bf16(wb, bf, acc1, 0,0,0);
    }
    {
      b8v bb;
      #pragma unroll
      for (int j=0;j<8;j++) bb[j] = (__bf16)silu_(v[j]);
      s8v wa = *(const s8v*)&Wbf[W3_OFF + fn*288      + 256 + kg*8];
      s8v wb = *(const s8v*)&Wbf[W3_OFF + (16+fn)*288 + 256 + kg*8];
      acc0 = __builtin_amdgcn_mfma_f32_16x16x32_bf16(wa, b2s(bb), acc0, 0,0,0);
      acc1 = __builtin_amdgcn_mfma_f32_16x16x32_bf16(wb, b2s(bb), acc1, 0,0,0);
    }
    f4v za0 = *(const f4v*)&zA[r][kg*4],    zb0 = *(const f4v*)&zB[r][kg*4];
    f4v za1 = *(const f4v*)&zA[r][16+kg*4], zb1 = *(const f4v*)&zB[r][16+kg*4];
    *(f4v*)&zA[r][kg*4]    = acc0 + za0 + zb0;
    *(f4v*)&zA[r][16+kg*4] = acc1 + za1 + zb1;
  }
  __syncthreads();

  // ---- phase 5: GEMM4 (k4 on z=zA) + residual -> yw ----
  {
    const int r = wave*16 + fn;
    float v[8];
    #pragma unroll
    for (int ks=0;ks<8;ks++) v[ks] = zA[r][ks*4 + kg];
    float s1=0.f, s2=0.f;
    #pragma unroll
    for (int ks=0;ks<8;ks++){ s1 += v[ks]; s2 += v[ks]*v[ks]; }
    s1 += __shfl_xor(s1,16); s2 += __shfl_xor(s2,16);
    s1 += __shfl_xor(s1,32); s2 += __shfl_xor(s2,32);
    float mu  = s1*(1.0f/32.0f);
    float var = s2*(1.0f/32.0f) - mu*mu;
    float rs  = rsqrtf(var + 1e-5f);

    f4v acc0 = *(const f4v*)&k4_bb[kg*4];
    f4v acc1 = *(const f4v*)&k4_bb[16 + kg*4];
    #pragma unroll
    for (int ks=0;ks<8;ks++){
      float lnv = (v[ks]-mu)*rs*k4_ln_g[ks*4+kg] + k4_ln_b[ks*4+kg];
      s8v bf = b2s(basis8bf_(lnv));
      s8v wa = *(const s8v*)&Wbf[W4_OFF + fn*288      + ks*32 + kg*8];
      s8v wb = *(const s8v*)&Wbf[W4_OFF + (16+fn)*288 + ks*32 + kg*8];
      acc0 = __builtin_amdgcn_mfma_f32_16x16x32_bf16(wa, bf, acc0, 0,0,0);
      acc1 = __builtin_amdgcn_mfma_f32_16x16x32_bf16(wb, bf, acc1, 0,0,0);
    }
    {
      b8v bb;
      #pragma unroll
      for (int j=0;j<8;j++) bb[j] = (__bf16)silu_(v[j]);
      s8v wa = *(const s8v*)&Wbf[W4_OFF + fn*288      + 256 + kg*8];
      s8v wb = *(const s8v*)&Wbf[W4_OFF + (16+fn)*288 + 256 + kg*8];
      acc0 = __builtin_amdgcn_mfma_f32_16x16x32_bf16(wa, b2s(bb), acc0, 0,0,0);
      acc1 = __builtin_amdgcn_mfma_f32_16x16x32_bf16(wb, b2s(bb), acc1, 0,0,0);
    }
    f4v x0 = *(const f4v*)&xw[r][kg*4],    x1 = *(const f4v*)&xw[r][16+kg*4];
    *(f4v*)&yw[r][kg*4]    = acc0 + x0;
    *(f4v*)&yw[r][16+kg*4] = acc1 + x1;
  }
  __syncthreads();

  // ---- phase 6: coalesced store ----
  {
    int ch = t & 31, h = t >> 5;
    float* dst = out + (((size_t)(b*32 + ch)*256 + (h0+h))*256 + w0);
    int p = h*8;
    float4 v0 = { yw[p+0][ch], yw[p+1][ch], yw[p+2][ch], yw[p+3][ch] };
    float4 v1 = { yw[p+4][ch], yw[p+5][ch], yw[p+6][ch], yw[p+7][ch] };
    *(float4*)(dst)     = v0;
    *(float4*)(dst + 4) = v1;
  }
}

extern "C" void kernel_launch(void* const* d_in, const int* in_sizes, int n_in,
                              void* d_out, int out_size, void* d_ws, size_t ws_size,
                              hipStream_t stream) {
  const float* x      = (const float*)d_in[0];
  const float* pn_g   = (const float*)d_in[1];
  const float* pn_b   = (const float*)d_in[2];
  const float* k1_ln_g= (const float*)d_in[3];
  const float* k1_ln_b= (const float*)d_in[4];
  const float* k1_ws  = (const float*)d_in[5];
  const float* k1_wb  = (const float*)d_in[6];
  const float* k1_bb  = (const float*)d_in[7];
  const float* k2_ln_g= (const float*)d_in[8];
  const float* k2_ln_b= (const float*)d_in[9];
  const float* k2_ws  = (const float*)d_in[10];
  const float* k2_wb  = (const float*)d_in[11];
  const float* k2_bb  = (const float*)d_in[12];
  const float* k3_ln_g= (const float*)d_in[13];
  const float* k3_ln_b= (const float*)d_in[14];
  const float* k3_ws  = (const float*)d_in[15];
  const float* k3_wb  = (const float*)d_in[16];
  const float* k3_bb  = (const float*)d_in[17];
  const float* k4_ln_g= (const float*)d_in[18];
  const float* k4_ln_b= (const float*)d_in[19];
  const float* k4_ws  = (const float*)d_in[20];
  const float* k4_wb  = (const float*)d_in[21];
  const float* k4_bb  = (const float*)d_in[22];
  float* out = (float*)d_out;
  __bf16* Wbf = (__bf16*)d_ws;

  hipLaunchKernelGGL(prep_w, dim3((W_TOTAL+255)/256), dim3(256), 0, stream,
                     k1_ws, k1_wb, k2_ws, k2_wb, k3_ws, k3_wb, k4_ws, k4_wb, Wbf);

  hipLaunchKernelGGL(swin_kan_mfma, dim3(4096), dim3(256), 0, stream,
                     x, pn_g, pn_b,
                     k1_ln_g, k1_ln_b, k1_bb,
                     k2_ln_g, k2_ln_b, k2_bb,
                     k3_ln_g, k3_ln_b, k3_bb,
                     k4_ln_g, k4_ln_b, k4_bb,
                     Wbf, out);
}